// Round 7
// baseline (352.050 us; speedup 1.0000x reference)
//
#include <hip/hip_runtime.h>

typedef __bf16 bf16x8 __attribute__((ext_vector_type(8)));
typedef __bf16 bf16x4 __attribute__((ext_vector_type(4)));
typedef float  f32x4  __attribute__((ext_vector_type(4)));

#define EMB 512
#define NROWS 256
#define BNC 32          // classes per chunk
#define NBLK 512        // persistent blocks (2 per CU)
#define NCOPY 16
// 32 * log2(e)
#define K_SCALE_LOG2E 46.16624130844683f
#define SIN_M_ 0.479425538604203f
#define PI_ 3.14159265358979323846f

__device__ __forceinline__ unsigned short f2bf(float f) {
    union { float f; unsigned u; } x; x.f = f;
    return (unsigned short)((x.u + 0x7FFFu + ((x.u >> 16) & 1u)) >> 16);
}

// XOR-swizzle on LDS byte offsets within one 32KB buffer: folds row bits
// (10..12) and bits (8..9) into the 16B-slot bits (4..6). Involution,
// bijective, preserves 8B/16B contiguity. GF(2)-checked for the BNC=32
// shapes: stage ds_write (8B) -> uniform 4 lanes/slot (min); MFMA
// ds_read_b128 -> uniform 8 lanes/slot (min).
__device__ __forceinline__ int swz(int logical) {
    return logical ^ ((((logical >> 10) & 7) ^ ((logical >> 8) & 3)) << 4);
}

// ---- K1: fused: normalize features -> bf16 A; exact f32 cos_y; zero expsum ----
__global__ void prep_kernel(const float* __restrict__ F, const int* __restrict__ labels,
                            const float* __restrict__ W,
                            unsigned short* __restrict__ Abf,
                            float* __restrict__ cos_y, float* __restrict__ expsum) {
    const int row = blockIdx.x, t = threadIdx.x;
    const int lbl = labels[row];
    float2 fv = reinterpret_cast<const float2*>(F + (size_t)row * EMB)[t];
    float2 wv = reinterpret_cast<const float2*>(W + (size_t)lbl * EMB)[t];
    float ff = fv.x * fv.x + fv.y * fv.y;
    float fw = fv.x * wv.x + fv.y * wv.y;
    float ww = wv.x * wv.x + wv.y * wv.y;
    #pragma unroll
    for (int m = 1; m < 64; m <<= 1) {
        ff += __shfl_xor(ff, m); fw += __shfl_xor(fw, m); ww += __shfl_xor(ww, m);
    }
    __shared__ float sf[4], sb[4], sc[4];
    if ((t & 63) == 0) { int w = t >> 6; sf[w] = ff; sb[w] = fw; sc[w] = ww; }
    __syncthreads();
    const float a = sf[0] + sf[1] + sf[2] + sf[3];
    const float inv = 1.f / fmaxf(sqrtf(a), 1e-12f);
    ushort2 o; o.x = f2bf(fv.x * inv); o.y = f2bf(fv.y * inv);
    reinterpret_cast<ushort2*>(Abf + (size_t)row * EMB)[t] = o;
    if (t < NCOPY) expsum[t * NROWS + row] = 0.f;
    if (t == 0) {
        const float b = sb[0] + sb[1] + sb[2] + sb[3];
        const float c = sc[0] + sc[1] + sc[2] + sc[3];
        const float cs = b / (fmaxf(sqrtf(a), 1e-12f) * fmaxf(sqrtf(c), 1e-12f));
        cos_y[row] = fminf(fmaxf(cs, -1.f), 1.f);
    }
}

// ---- K2: persistent 2-phase-pipelined GEMM + exp-sum ----
// 512 threads = 8 waves; wave w owns rows [w*32, w*32+32) x 32 classes/chunk.
// Double-buffered 32KB LDS tiles; per iteration: issue loads(next) ->
// compute(cur) -> cvt+write(next) -> ONE barrier. Exp-sums accumulate in
// registers across chunks; one atomic set per block at the end.
__global__ __launch_bounds__(512, 4) void gemm_lse(
    const unsigned short* __restrict__ A,  // [256][512] bf16 (normalized features)
    const float* __restrict__ W,           // [C][512] raw f32
    float* __restrict__ expsum,            // [NCOPY][256] f32
    int C) {
    __shared__ unsigned short sW[2][BNC * EMB];   // 2 x 32KB swizzled bf16 tiles
    __shared__ float s_invw[2][BNC];

    const int t = threadIdx.x;
    const int bid = blockIdx.x;
    const int nchunk = (C + BNC - 1) / BNC;   // 3125 (exact, no tail for C=100000)
    const int cls_l = t >> 4;       // 0..31 local class (16 lanes per class)
    const int slice = t & 15;       // 0..15
    const int wave = t >> 6;
    const int lane = t & 63;
    const int g = lane >> 4;        // k-group
    const int r16 = lane & 15;      // row (A) / class (B) within 16-block

    float rsacc[2][4];              // per-lane running exp-sums [mb][r]
    #pragma unroll
    for (int mb = 0; mb < 2; ++mb)
        #pragma unroll
        for (int r = 0; r < 4; ++r) rsacc[mb][r] = 0.f;

    char* sb0 = reinterpret_cast<char*>(&sW[0][0]);
    char* sb1 = reinterpret_cast<char*>(&sW[1][0]);

    // ---- prologue: stage chunk `bid` into buffer 0 ----
    int c = bid;
    float4 vr[8];
    if (c < nchunk) {
        const int cg = c * BNC + cls_l;
        const bool v = (cg < C);
        const float4* src = reinterpret_cast<const float4*>(
            W + (size_t)(v ? cg : 0) * EMB);
        #pragma unroll
        for (int i = 0; i < 8; ++i) vr[i] = src[i * 16 + slice];
        float ss = 0.f;
        #pragma unroll
        for (int i = 0; i < 8; ++i) {
            float4 x = vr[i];
            if (!v) { x.x = 0.f; x.y = 0.f; x.z = 0.f; x.w = 0.f; }
            ss += x.x * x.x + x.y * x.y + x.z * x.z + x.w * x.w;
            bf16x4 p;
            p.x = (__bf16)x.x; p.y = (__bf16)x.y; p.z = (__bf16)x.z; p.w = (__bf16)x.w;
            *reinterpret_cast<bf16x4*>(sb0 + swz(cls_l * 1024 + i * 128 + slice * 8)) = p;
        }
        ss += __shfl_xor(ss, 1);
        ss += __shfl_xor(ss, 2);
        ss += __shfl_xor(ss, 4);
        ss += __shfl_xor(ss, 8);
        if (slice == 0) s_invw[0][cls_l] = v ? 1.f / fmaxf(sqrtf(ss), 1e-12f) : 0.f;
    }
    __syncthreads();

    int cur = 0;
    while (c < nchunk) {
        const int nc = c + NBLK;
        const bool hn = (nc < nchunk);

        // ---- issue next chunk's loads early (consumed after compute) ----
        bool v2 = false;
        if (hn) {
            const int cg = nc * BNC + cls_l;
            v2 = (cg < C);
            const float4* src = reinterpret_cast<const float4*>(
                W + (size_t)(v2 ? cg : 0) * EMB);
            #pragma unroll
            for (int i = 0; i < 8; ++i) vr[i] = src[i * 16 + slice];
        }

        // ---- compute chunk c on buffer cur ----
        const char* sb = cur ? sb1 : sb0;
        f32x4 acc[2][2];
        #pragma unroll
        for (int mb = 0; mb < 2; ++mb)
            #pragma unroll
            for (int nb = 0; nb < 2; ++nb) acc[mb][nb] = f32x4{0.f, 0.f, 0.f, 0.f};

        #pragma unroll 4
        for (int kk = 0; kk < EMB / 32; ++kk) {
            bf16x8 bfr[2], afr[2];
            #pragma unroll
            for (int nb = 0; nb < 2; ++nb) {
                const int logical = (nb * 16 + r16) * 1024 + kk * 64 + g * 16;
                bfr[nb] = *reinterpret_cast<const bf16x8*>(sb + swz(logical));
            }
            #pragma unroll
            for (int mb = 0; mb < 2; ++mb) {
                const int row = wave * 32 + mb * 16 + r16;
                afr[mb] = *reinterpret_cast<const bf16x8*>(
                    A + (size_t)row * EMB + kk * 32 + g * 8);
            }
            #pragma unroll
            for (int mb = 0; mb < 2; ++mb)
                #pragma unroll
                for (int nb = 0; nb < 2; ++nb)
                    acc[mb][nb] = __builtin_amdgcn_mfma_f32_16x16x32_bf16(
                        afr[mb], bfr[nb], acc[mb][nb], 0, 0, 0);
        }

        // ---- fold this chunk into the running exp-sums ----
        {
            const float iw0 = s_invw[cur][r16];
            const float iw1 = s_invw[cur][16 + r16];
            const float m0 = ((c * BNC + r16) < C) ? 1.f : 0.f;
            const float m1 = ((c * BNC + 16 + r16) < C) ? 1.f : 0.f;
            #pragma unroll
            for (int mb = 0; mb < 2; ++mb) {
                #pragma unroll
                for (int r = 0; r < 4; ++r) {
                    float cs0 = fminf(fmaxf(acc[mb][0][r] * iw0, -1.f), 1.f);
                    float cs1 = fminf(fmaxf(acc[mb][1][r] * iw1, -1.f), 1.f);
                    rsacc[mb][r] += m0 * exp2f(cs0 * K_SCALE_LOG2E - K_SCALE_LOG2E)
                                  + m1 * exp2f(cs1 * K_SCALE_LOG2E - K_SCALE_LOG2E);
                }
            }
        }

        // ---- convert + write next chunk into the other buffer ----
        if (hn) {
            char* sbn = cur ? sb0 : sb1;
            float ss = 0.f;
            #pragma unroll
            for (int i = 0; i < 8; ++i) {
                float4 x = vr[i];
                if (!v2) { x.x = 0.f; x.y = 0.f; x.z = 0.f; x.w = 0.f; }
                ss += x.x * x.x + x.y * x.y + x.z * x.z + x.w * x.w;
                bf16x4 p;
                p.x = (__bf16)x.x; p.y = (__bf16)x.y; p.z = (__bf16)x.z; p.w = (__bf16)x.w;
                *reinterpret_cast<bf16x4*>(sbn + swz(cls_l * 1024 + i * 128 + slice * 8)) = p;
            }
            ss += __shfl_xor(ss, 1);
            ss += __shfl_xor(ss, 2);
            ss += __shfl_xor(ss, 4);
            ss += __shfl_xor(ss, 8);
            if (slice == 0) s_invw[cur ^ 1][cls_l] = v2 ? 1.f / fmaxf(sqrtf(ss), 1e-12f) : 0.f;
        }
        __syncthreads();
        cur ^= 1;
        c = nc;
    }

    // ---- block epilogue: reduce running sums, one atomic set ----
    float* dst = expsum + (bid & (NCOPY - 1)) * NROWS;
    #pragma unroll
    for (int mb = 0; mb < 2; ++mb) {
        #pragma unroll
        for (int r = 0; r < 4; ++r) {
            float rs = rsacc[mb][r];
            rs += __shfl_xor(rs, 1);
            rs += __shfl_xor(rs, 2);
            rs += __shfl_xor(rs, 4);
            rs += __shfl_xor(rs, 8);
            if (r16 == 0) atomicAdd(&dst[wave * 32 + mb * 16 + g * 4 + r], rs);
        }
    }
}

// ---- K3: fused: quantile (order-stat 51 of 256) + margins + patch + LSE + mean ----
// jnp.quantile(d, 0.2) over 256: pos = f32(0.2)*255 rounds to exactly 51.0f
// -> frac 0 -> sorted[51]; rank-selection below reproduces it bit-exactly.
__global__ void finish_kernel(const float* __restrict__ cos_y,
                              const float* __restrict__ expsum,
                              float* __restrict__ out) {
    __shared__ float sd[NROWS];
    __shared__ float s_thr;
    __shared__ float s[4];
    const int i = threadIdx.x;
    const float cy = cos_y[i];
    const float d = 1.f - cy;
    sd[i] = d;
    __syncthreads();
    int lt = 0, eq = 0;
    for (int j = 0; j < NROWS; ++j) {
        const float dj = sd[j];
        lt += (dj < d); eq += (dj == d);
    }
    if (lt <= 51 && 51 < lt + eq) s_thr = d;   // exactly one distinct value qualifies
    __syncthreads();
    const float hard = (d >= s_thr) ? 1.f : 0.f;
    const float m = 0.5f + 0.1f * d + 0.15f * hard;
    const float cosm = cy - m * SIN_M_ - (1.f - cosf(m * PI_)) * cy;
    const float sub = exp2f(cy   * K_SCALE_LOG2E - K_SCALE_LOG2E);
    const float add = exp2f(cosm * K_SCALE_LOG2E - K_SCALE_LOG2E);
    float S = 0.f;
    #pragma unroll
    for (int cc = 0; cc < NCOPY; ++cc) S += expsum[cc * NROWS + i];
    S += add - sub;
    float term = 32.f + logf(S) - 32.f * cosm;
    #pragma unroll
    for (int mm = 1; mm < 64; mm <<= 1) term += __shfl_xor(term, mm);
    if ((i & 63) == 0) s[i >> 6] = term;
    __syncthreads();
    if (i == 0) out[0] = (s[0] + s[1] + s[2] + s[3]) * (1.f / 256.f);
}

extern "C" void kernel_launch(void* const* d_in, const int* in_sizes, int n_in,
                              void* d_out, int out_size, void* d_ws, size_t ws_size,
                              hipStream_t stream) {
    (void)n_in; (void)out_size; (void)ws_size;
    const float* F      = (const float*)d_in[0];
    const int*   labels = (const int*)d_in[1];
    const float* W      = (const float*)d_in[2];
    float* out = (float*)d_out;
    const int C = in_sizes[2] / EMB;             // 100000

    char* ws = (char*)d_ws;
    unsigned short* Abf = (unsigned short*)ws;   // 256*512*2 = 262144 B
    float* cos_y  = (float*)(ws + 262144);       // 256 f32
    float* expsum = cos_y + NROWS;               // NCOPY*256 f32

    hipLaunchKernelGGL(prep_kernel,   dim3(NROWS), dim3(256), 0, stream,
                       F, labels, W, Abf, cos_y, expsum);
    hipLaunchKernelGGL(gemm_lse,      dim3(NBLK),  dim3(512), 0, stream, Abf, W, expsum, C);
    hipLaunchKernelGGL(finish_kernel, dim3(1),     dim3(256), 0, stream,
                       cos_y, expsum, out);
}

// Round 11
// 298.260 us; speedup vs baseline: 1.1803x; 1.1803x over previous
//
#include <hip/hip_runtime.h>

typedef __bf16 bf16x8 __attribute__((ext_vector_type(8)));
typedef float  f32x4  __attribute__((ext_vector_type(4)));

#define EMB 512
#define NROWS 256
#define BNC 16              // classes per chunk
#define GRID 256            // persistent blocks, 1 per CU
#define NBUF 4              // 4 x 32KB f32 LDS buffers, prefetch depth 3
#define NCOPY 16
// 32 * log2(e)
#define K_SCALE_LOG2E 46.16624130844683f
#define SIN_M_ 0.479425538604203f
#define PI_ 3.14159265358979323846f

__device__ __forceinline__ unsigned short f2bf(float f) {
    union { float f; unsigned u; } x; x.f = f;
    return (unsigned short)((x.u + 0x7FFFu + ((x.u >> 16) & 1u)) >> 16);
}

// ---- K1: fused: normalize features -> bf16 A; exact f32 cos_y; zero expsum ----
__global__ void prep_kernel(const float* __restrict__ F, const int* __restrict__ labels,
                            const float* __restrict__ W,
                            unsigned short* __restrict__ Abf,
                            float* __restrict__ cos_y, float* __restrict__ expsum) {
    const int row = blockIdx.x, t = threadIdx.x;
    const int lbl = labels[row];
    float2 fv = reinterpret_cast<const float2*>(F + (size_t)row * EMB)[t];
    float2 wv = reinterpret_cast<const float2*>(W + (size_t)lbl * EMB)[t];
    float ff = fv.x * fv.x + fv.y * fv.y;
    float fw = fv.x * wv.x + fv.y * wv.y;
    float ww = wv.x * wv.x + wv.y * wv.y;
    #pragma unroll
    for (int m = 1; m < 64; m <<= 1) {
        ff += __shfl_xor(ff, m); fw += __shfl_xor(fw, m); ww += __shfl_xor(ww, m);
    }
    __shared__ float sf[4], sb[4], sc[4];
    if ((t & 63) == 0) { int w = t >> 6; sf[w] = ff; sb[w] = fw; sc[w] = ww; }
    __syncthreads();
    const float a = sf[0] + sf[1] + sf[2] + sf[3];
    const float inv = 1.f / fmaxf(sqrtf(a), 1e-12f);
    ushort2 o; o.x = f2bf(fv.x * inv); o.y = f2bf(fv.y * inv);
    reinterpret_cast<ushort2*>(Abf + (size_t)row * EMB)[t] = o;
    if (t < NCOPY) expsum[t * NROWS + row] = 0.f;
    if (t == 0) {
        const float b = sb[0] + sb[1] + sb[2] + sb[3];
        const float c = sc[0] + sc[1] + sc[2] + sc[3];
        const float cs = b / (fmaxf(sqrtf(a), 1e-12f) * fmaxf(sqrtf(c), 1e-12f));
        cos_y[row] = fminf(fmaxf(cs, -1.f), 1.f);
    }
}

// Stage one 16-class chunk (32KB f32) via async global_load_lds.
// LDS dest is LINEAR (HW: wave-uniform base + lane*16); the XOR-swizzle is
// applied by permuting the GLOBAL source segment per lane (lane ^ (c&7)) —
// rule 21: both-sides-or-neither. Reads apply the same involution.
__device__ __forceinline__ void stage_chunk(const float* __restrict__ W, int C, int chunk,
                                            char* buf, int wave, int lane) {
    #pragma unroll
    for (int it = 0; it < 4; ++it) {
        const int wi = wave * 4 + it;   // 1KB window 0..31
        const int c  = wi >> 1;         // local class 0..15
        const int h  = wi & 1;          // half-row
        int cg = chunk * BNC + c;
        if (cg >= C) cg = 0;            // never triggers for C=100000
        const float* gp = W + (size_t)cg * EMB + h * 256 + ((lane ^ (c & 7)) << 2);
        __builtin_amdgcn_global_load_lds(
            (const __attribute__((address_space(1))) void*)gp,
            (__attribute__((address_space(3))) void*)(buf + wi * 1024),
            16, 0, 0);
    }
}

// ---- K2: persistent async-DMA GEMM + exp-sum ----
// 512 thr = 8 waves, 1 block/CU (128KB LDS). Depth-3 global_load_lds
// prefetch with counted vmcnt (never 0 in steady state) + raw s_barrier.
// A fragments hoisted to 128 VGPRs once -> compute phase has NO global
// loads, so compiler vmcnt insertion cannot drain the DMA queue (any
// compiler wait for the A-hoist is vmcnt(>=12), weaker than ours).
__global__ __launch_bounds__(512, 2) void gemm_lse(
    const unsigned short* __restrict__ A,  // [256][512] bf16 normalized features
    const float* __restrict__ W,           // [C][512] raw f32
    float* __restrict__ expsum,            // [NCOPY][256] f32
    int C) {
    __shared__ float sW[NBUF * BNC * EMB];   // 4 x 32KB, swizzled f32 tiles
    __shared__ float s_invw[BNC];

    const int t = threadIdx.x;
    const int bid = blockIdx.x;
    const int wave = t >> 6;
    const int lane = t & 63;
    const int g = lane >> 4;        // k-group
    const int r16 = lane & 15;      // row (A) / class (B) within 16-block
    const int NCH = (C + BNC - 1) / BNC;     // 6250
    char* sWc = reinterpret_cast<char*>(sW);

    // ---- hoist A fragments (loop-invariant, 128 VGPRs) ----
    bf16x8 afr0[16], afr1[16];
    {
        const unsigned short* a0 = A + (size_t)(wave * 32 + r16) * EMB + g * 8;
        const unsigned short* a1 = A + (size_t)(wave * 32 + 16 + r16) * EMB + g * 8;
        #pragma unroll
        for (int kk = 0; kk < 16; ++kk) {
            afr0[kk] = *reinterpret_cast<const bf16x8*>(a0 + kk * 32);
            afr1[kk] = *reinterpret_cast<const bf16x8*>(a1 + kk * 32);
        }
    }

    float rs0[4] = {0.f, 0.f, 0.f, 0.f};
    float rs1[4] = {0.f, 0.f, 0.f, 0.f};

    // ---- prologue: prefetch up to 3 chunks ----
    int j  = bid;       // current chunk
    int jp = bid;       // next chunk to issue
    #pragma unroll
    for (int d = 0; d < NBUF - 1; ++d) {
        if (jp < NCH) {
            stage_chunk(W, C, jp, sWc + (((jp - bid) >> 8) & (NBUF - 1)) * 32768, wave, lane);
            jp += GRID;
        }
    }

    while (j < NCH) {
        // wait for chunk j's DMA (own-wave count; barrier makes it block-wide)
        const int inflight = (jp - j) >> 8;      // 1..3, block-uniform
        if (inflight >= 3)      asm volatile("s_waitcnt vmcnt(8) lgkmcnt(0)" ::: "memory");
        else if (inflight == 2) asm volatile("s_waitcnt vmcnt(4) lgkmcnt(0)" ::: "memory");
        else                    asm volatile("s_waitcnt vmcnt(0) lgkmcnt(0)" ::: "memory");
        __builtin_amdgcn_s_barrier();
        __builtin_amdgcn_sched_barrier(0);   // rule 18: pin — nothing crosses the wait

        char* buf = sWc + (((j - bid) >> 8) & (NBUF - 1)) * 32768;

        // issue prefetch for j+3 into the buffer freed at this barrier
        if (jp < NCH) {
            stage_chunk(W, C, jp, sWc + (((jp - bid) >> 8) & (NBUF - 1)) * 32768, wave, lane);
            jp += GRID;
        }

        // ---- per-class 1/||w||: wave w handles classes 2w, 2w+1 ----
        {
            const int c0 = wave * 2 + (lane >> 5);
            const int li = lane & 31;
            const char* tb = buf + c0 * 2048;
            const int mr = (c0 & 7) << 4;
            float ssum = 0.f;
            #pragma unroll
            for (int s = 0; s < 4; ++s) {
                float4 v = *reinterpret_cast<const float4*>(tb + ((s * 512 + li * 16) ^ mr));
                ssum += v.x * v.x + v.y * v.y + v.z * v.z + v.w * v.w;
            }
            ssum += __shfl_xor(ssum, 1);
            ssum += __shfl_xor(ssum, 2);
            ssum += __shfl_xor(ssum, 4);
            ssum += __shfl_xor(ssum, 8);
            ssum += __shfl_xor(ssum, 16);
            if (li == 0) s_invw[c0] = 1.f / fmaxf(sqrtf(ssum), 1e-12f);
        }
        asm volatile("s_waitcnt lgkmcnt(0)" ::: "memory");
        __builtin_amdgcn_s_barrier();
        __builtin_amdgcn_sched_barrier(0);   // rule 18

        // ---- MFMA over K=512, cvt f32->bf16 per fragment in regs ----
        f32x4 acc0 = {0.f, 0.f, 0.f, 0.f};
        f32x4 acc1 = {0.f, 0.f, 0.f, 0.f};
        const char* bb = buf + r16 * 2048;
        const int off0 = (g << 5) ^ ((r16 & 7) << 4);
        #pragma unroll
        for (int kk = 0; kk < 16; ++kk) {
            float4 lo = *reinterpret_cast<const float4*>(bb + kk * 128 + off0);
            float4 hi = *reinterpret_cast<const float4*>(bb + kk * 128 + (off0 ^ 16));
            bf16x8 bf;
            bf[0] = (__bf16)lo.x; bf[1] = (__bf16)lo.y; bf[2] = (__bf16)lo.z; bf[3] = (__bf16)lo.w;
            bf[4] = (__bf16)hi.x; bf[5] = (__bf16)hi.y; bf[6] = (__bf16)hi.z; bf[7] = (__bf16)hi.w;
            acc0 = __builtin_amdgcn_mfma_f32_16x16x32_bf16(afr0[kk], bf, acc0, 0, 0, 0);
            acc1 = __builtin_amdgcn_mfma_f32_16x16x32_bf16(afr1[kk], bf, acc1, 0, 0, 0);
        }

        // ---- fold into running exp-sums ----
        {
            const float iw = s_invw[r16];
            const float mk = ((j * BNC + r16) < C) ? 1.f : 0.f;
            #pragma unroll
            for (int r = 0; r < 4; ++r) {
                float c0v = fminf(fmaxf(acc0[r] * iw, -1.f), 1.f);
                float c1v = fminf(fmaxf(acc1[r] * iw, -1.f), 1.f);
                rs0[r] += mk * exp2f(c0v * K_SCALE_LOG2E - K_SCALE_LOG2E);
                rs1[r] += mk * exp2f(c1v * K_SCALE_LOG2E - K_SCALE_LOG2E);
            }
        }
        j += GRID;
    }

    // ---- epilogue: reduce over r16, one atomic set per block ----
    float* dst = expsum + (bid & (NCOPY - 1)) * NROWS;
    #pragma unroll
    for (int r = 0; r < 4; ++r) {
        float a0v = rs0[r], a1v = rs1[r];
        a0v += __shfl_xor(a0v, 1); a0v += __shfl_xor(a0v, 2);
        a0v += __shfl_xor(a0v, 4); a0v += __shfl_xor(a0v, 8);
        a1v += __shfl_xor(a1v, 1); a1v += __shfl_xor(a1v, 2);
        a1v += __shfl_xor(a1v, 4); a1v += __shfl_xor(a1v, 8);
        if (r16 == 0) {
            atomicAdd(&dst[wave * 32 + g * 4 + r], a0v);
            atomicAdd(&dst[wave * 32 + 16 + g * 4 + r], a1v);
        }
    }
}

// ---- K3: fused: quantile (order-stat 51 of 256) + margins + patch + LSE + mean ----
__global__ void finish_kernel(const float* __restrict__ cos_y,
                              const float* __restrict__ expsum,
                              float* __restrict__ out) {
    __shared__ float sd[NROWS];
    __shared__ float s_thr;
    __shared__ float s[4];
    const int i = threadIdx.x;
    const float cy = cos_y[i];
    const float d = 1.f - cy;
    sd[i] = d;
    __syncthreads();
    int lt = 0, eq = 0;
    for (int jj = 0; jj < NROWS; ++jj) {
        const float dj = sd[jj];
        lt += (dj < d); eq += (dj == d);
    }
    if (lt <= 51 && 51 < lt + eq) s_thr = d;
    __syncthreads();
    const float hard = (d >= s_thr) ? 1.f : 0.f;
    const float m = 0.5f + 0.1f * d + 0.15f * hard;
    const float cosm = cy - m * SIN_M_ - (1.f - cosf(m * PI_)) * cy;
    const float sub = exp2f(cy   * K_SCALE_LOG2E - K_SCALE_LOG2E);
    const float add = exp2f(cosm * K_SCALE_LOG2E - K_SCALE_LOG2E);
    float S = 0.f;
    #pragma unroll
    for (int cc = 0; cc < NCOPY; ++cc) S += expsum[cc * NROWS + i];
    S += add - sub;
    float term = 32.f + logf(S) - 32.f * cosm;
    #pragma unroll
    for (int mm = 1; mm < 64; mm <<= 1) term += __shfl_xor(term, mm);
    if ((i & 63) == 0) s[i >> 6] = term;
    __syncthreads();
    if (i == 0) out[0] = (s[0] + s[1] + s[2] + s[3]) * (1.f / 256.f);
}

extern "C" void kernel_launch(void* const* d_in, const int* in_sizes, int n_in,
                              void* d_out, int out_size, void* d_ws, size_t ws_size,
                              hipStream_t stream) {
    (void)n_in; (void)out_size; (void)ws_size;
    const float* F      = (const float*)d_in[0];
    const int*   labels = (const int*)d_in[1];
    const float* W      = (const float*)d_in[2];
    float* out = (float*)d_out;
    const int C = in_sizes[2] / EMB;             // 100000

    char* ws = (char*)d_ws;
    unsigned short* Abf = (unsigned short*)ws;   // 256*512*2 = 262144 B
    float* cos_y  = (float*)(ws + 262144);       // 256 f32
    float* expsum = cos_y + NROWS;               // NCOPY*256 f32

    hipLaunchKernelGGL(prep_kernel,   dim3(NROWS), dim3(256), 0, stream,
                       F, labels, W, Abf, cos_y, expsum);
    hipLaunchKernelGGL(gemm_lse,      dim3(GRID),  dim3(512), 0, stream, Abf, W, expsum, C);
    hipLaunchKernelGGL(finish_kernel, dim3(1),     dim3(256), 0, stream,
                       cos_y, expsum, out);
}